// Round 6
// baseline (2618.840 us; speedup 1.0000x reference)
//
#include <hip/hip_runtime.h>

#define H 51
#define TSEQ 2048
#define BB 16            // batch per block — fills all 16 MFMA columns
#define THREADS 512      // 8 waves, 2 tile-slots each, 2 waves/SIMD

typedef __attribute__((ext_vector_type(8))) short short8;   // 8 bf16 (MFMA A/B frag)
typedef __attribute__((ext_vector_type(4))) float float4v;  // MFMA C/D frag

#define LOG2E    1.44269504f
#define TWOLOG2E 2.88539008f

__device__ __forceinline__ float sig_pre(float u) {   // sigmoid(g), u = g*log2e
    return __builtin_amdgcn_rcpf(1.0f + __builtin_amdgcn_exp2f(-u));
}
__device__ __forceinline__ float tanh_pre(float u) {  // tanh(g),  u = g*2log2e
    return 1.0f - 2.0f * __builtin_amdgcn_rcpf(1.0f + __builtin_amdgcn_exp2f(u));
}
__device__ __forceinline__ unsigned short bf16_rne(float x) {
    unsigned u = __float_as_uint(x);
    u += 0x7FFF + ((u >> 16) & 1);
    return (unsigned short)(u >> 16);
}
__device__ __forceinline__ float bf16f(unsigned short h) {
    return __uint_as_float(((unsigned)h) << 16);
}

// Rotated schedule: body(t) = {load frags; [y(t-1) wave7]; mm2(t)+ew2(t) ||
// mm1(t+1)+ew1(t+1); barrier}. The two chains are independent -> scheduler
// interleaves. Branch-free: dummy slots (tiles 13-15, pad cell j=51) compute
// with zero weights and write into k-pad LDS positions whose A-columns are
// zero, so garbage never propagates.
// A rows repacked [i_j,f_j,g_j,o_j] per cell -> C/D reg r == gate r.
__global__ __launch_bounds__(THREADS, 2)
void lstm_rot_kernel(const float* __restrict__ input,
                     const float* __restrict__ W_ih1, const float* __restrict__ W_hh1,
                     const float* __restrict__ b_ih1, const float* __restrict__ b_hh1,
                     const float* __restrict__ W_ih2, const float* __restrict__ W_hh2,
                     const float* __restrict__ b_ih2, const float* __restrict__ b_hh2,
                     const float* __restrict__ W_lin, const float* __restrict__ b_lin,
                     float* __restrict__ out)
{
    // [parity][plane hi/lo][kstep][fraglane]; k-pad (k>=51) may hold garbage
    __shared__ short8 hb1[2][2][2][64];
    __shared__ short8 hb2[2][2][2][64];
    __shared__ float  h2f[2][64 * 16];    // fp32 h2 (padded to j<64 for dummy writes)
    __shared__ float  xss[2][64 * 17];    // x chunks, stride 17 conflict-free
    __shared__ float  ybf[BB][64];        // y buffer (wave7-private)
    __shared__ float  wlin[H + 1];

    const int tid  = threadIdx.x;
    const int wv   = tid >> 6;            // 0..7
    const int lane = tid & 63;
    const int n    = lane & 15;           // MFMA col = batch
    const int qd   = lane >> 4;           // quad
    const int b0   = blockIdx.x * BB;

    {   // zero both parities of h-state (512 short8 per array == THREADS)
        short8 z = {0,0,0,0,0,0,0,0};
        (&hb1[0][0][0][0])[tid] = z;
        (&hb2[0][0][0][0])[tid] = z;
    }
    if (tid < H)  wlin[tid] = W_lin[tid];
    if (tid == H) wlin[H]   = b_lin[0];

    // x chunk 0
#pragma unroll
    for (int r = 0; r < 2; ++r) {
        int b = wv + 8 * r;
        xss[0][lane * 17 + b] = input[(size_t)(b0 + b) * TSEQ + lane];
    }

    // ---- persistent A-fragments, split bf16 hi/lo, gate rows pre-scaled ----
    short8 wa1h[2][2], wa1l[2][2];        // W_hh1 (K=64)
    short8 wa2h[2][4], wa2l[2][4];        // s<2: W_ih2 (k=h1); s>=2: W_hh2 (k=h2)
#pragma unroll
    for (int i = 0; i < 2; ++i) {
        const int tile = wv + 8 * i;      // tiles 13..15 dummy (zero weights)
        const int arow = tile * 16 + n;
        const int cell = arow >> 2, gate = arow & 3;
        const int orow = gate * H + cell;
        const float gsc = (gate == 2) ? TWOLOG2E : LOG2E;
        const bool rok = (arow < 4 * H);
#pragma unroll
        for (int s = 0; s < 2; ++s) {
#pragma unroll
            for (int j = 0; j < 8; ++j) {
                int kk = s * 32 + qd * 8 + j;
                float w = (rok && kk < H) ? gsc * W_hh1[orow * H + kk] : 0.f;
                unsigned short hi = bf16_rne(w);
                wa1h[i][s][j] = (short)hi;
                wa1l[i][s][j] = (short)bf16_rne(w - bf16f(hi));
            }
        }
#pragma unroll
        for (int s = 0; s < 4; ++s) {
#pragma unroll
            for (int j = 0; j < 8; ++j) {
                int kk = s * 32 + qd * 8 + j;
                float w = 0.f;
                if (rok) {
                    if (kk < H)                       w = gsc * W_ih2[orow * H + kk];
                    else if (kk >= 64 && kk < 64 + H) w = gsc * W_hh2[orow * H + (kk - 64)];
                }
                unsigned short hi = bf16_rne(w);
                wa2h[i][s][j] = (short)hi;
                wa2l[i][s][j] = (short)bf16_rne(w - bf16f(hi));
            }
        }
    }

    // ---- per-lane elementwise constants (cell j = tile*4 + quad, j<64) ----
    float4v bias1v[2], wih1v[2], bias2v[2];
    int jj[2];
#pragma unroll
    for (int i = 0; i < 2; ++i) {
        const int tile = wv + 8 * i;
        const int j = tile * 4 + qd;
        jj[i] = j;
        const bool cok = (j < H);
#pragma unroll
        for (int r = 0; r < 4; ++r) {
            const float gsc = (r == 2) ? TWOLOG2E : LOG2E;
            const int orow = r * H + j;
            bias1v[i][r] = cok ? gsc * (b_ih1[orow] + b_hh1[orow]) : 0.f;
            wih1v[i][r]  = cok ? gsc * W_ih1[orow] : 0.f;
            bias2v[i][r] = cok ? gsc * (b_ih2[orow] + b_hh2[orow]) : 0.f;
        }
    }

    float c1[2] = {0.f, 0.f};
    float c2[2] = {0.f, 0.f};

    __syncthreads();   // zeros + wlin + x chunk 0 visible

    // ---- prologue: h1(0) = ew(bias1 + Wih1*x(0))   (h1(-1)=0 -> no MFMA) ----
    {
        const float xb = xss[0][n];
#pragma unroll
        for (int i = 0; i < 2; ++i) {
            float4v a;
#pragma unroll
            for (int r = 0; r < 4; ++r) a[r] = fmaf(wih1v[i][r], xb, bias1v[i][r]);
            float cn = fmaf(sig_pre(a[1]), c1[i], sig_pre(a[0]) * tanh_pre(a[2]));
            c1[i] = cn;
            float h = sig_pre(a[3]) * tanh_pre(cn * TWOLOG2E);
            int j = jj[i], s = j >> 5, q = (j & 31) >> 3, j7 = j & 7;
            unsigned short hi = bf16_rne(h);
            ((short*)&hb1[0][0][s][q * 16 + n])[j7] = (short)hi;
            ((short*)&hb1[0][1][s][q * 16 + n])[j7] = (short)bf16_rne(h - bf16f(hi));
        }
    }
    __syncthreads();   // h1(0) published

#pragma unroll 1
    for (int t = 0; t < TSEQ; ++t) {
        const int p = t & 1;

        // mid-chunk x prefetch (barrier-free double buffer)
        if ((t & 63) == 32 && t + 32 < TSEQ) {
            const int cp = (t >> 6) & 1;
#pragma unroll
            for (int r = 0; r < 2; ++r) {
                int b = wv + 8 * r;
                xss[cp ^ 1][lane * 17 + b] = input[(size_t)(b0 + b) * TSEQ + (t + 32) + lane];
            }
        }

        // ---- frag loads: h1(t) [parity p], h2(t-1) [parity p^1] ----
        short8 g1h[2], g1l[2], g2h[2], g2l[2];
#pragma unroll
        for (int s = 0; s < 2; ++s) {
            g1h[s] = hb1[p][0][s][lane];
            g1l[s] = hb1[p][1][s][lane];
            g2h[s] = hb2[p ^ 1][0][s][lane];
            g2l[s] = hb2[p ^ 1][1][s][lane];
        }

        // ---- y(t-1) + chunk flush: wave7 only ----
        if (wv == 7 && t > 0) {
            const int b = lane & 15, kg = lane >> 4;
            float a = 0.f;
#pragma unroll
            for (int it = 0; it < 13; ++it) {
                int j = kg + it * 4;
                if (j < H) a = fmaf(wlin[j], h2f[p ^ 1][j * 16 + b], a);
            }
            a += __shfl_xor(a, 16, 64);
            a += __shfl_xor(a, 32, 64);
            if (kg == 0) ybf[b][(t - 1) & 63] = a + wlin[H];
            if ((t & 63) == 0) {          // flush y[t-64 .. t-1]
                int tb = t - 64;
#pragma unroll
                for (int r = 0; r < BB; ++r)
                    out[(size_t)(b0 + r) * TSEQ + tb + lane] = ybf[r][lane];
            }
        }

        // ======== chain A: mm2(t) + ew2(t)  (uses g1=h1(t), g2=h2(t-1)) ========
        float4v a2[2];
#pragma unroll
        for (int i = 0; i < 2; ++i) a2[i] = bias2v[i];
#pragma unroll
        for (int s = 0; s < 2; ++s)
#pragma unroll
            for (int i = 0; i < 2; ++i) {
                a2[i] = __builtin_amdgcn_mfma_f32_16x16x32_bf16(wa2h[i][s], g1h[s], a2[i], 0, 0, 0);
                a2[i] = __builtin_amdgcn_mfma_f32_16x16x32_bf16(wa2h[i][s], g1l[s], a2[i], 0, 0, 0);
                a2[i] = __builtin_amdgcn_mfma_f32_16x16x32_bf16(wa2l[i][s], g1h[s], a2[i], 0, 0, 0);
            }
#pragma unroll
        for (int s = 0; s < 2; ++s)
#pragma unroll
            for (int i = 0; i < 2; ++i) {
                a2[i] = __builtin_amdgcn_mfma_f32_16x16x32_bf16(wa2h[i][s + 2], g2h[s], a2[i], 0, 0, 0);
                a2[i] = __builtin_amdgcn_mfma_f32_16x16x32_bf16(wa2h[i][s + 2], g2l[s], a2[i], 0, 0, 0);
                a2[i] = __builtin_amdgcn_mfma_f32_16x16x32_bf16(wa2l[i][s + 2], g2h[s], a2[i], 0, 0, 0);
            }

        // ======== chain B: mm1(t+1) + ew1(t+1)  (uses g1=h1(t), x(t+1)) ========
        // t=2047: writes garbage h1(2048) into hb1[0] — never read. Branch-free.
        const int t1 = t + 1;
        const float xb = xss[(t1 >> 6) & 1][(t1 & 63) * 17 + n];
        float4v a1[2];
#pragma unroll
        for (int i = 0; i < 2; ++i)
#pragma unroll
            for (int r = 0; r < 4; ++r)
                a1[i][r] = fmaf(wih1v[i][r], xb, bias1v[i][r]);
#pragma unroll
        for (int s = 0; s < 2; ++s)
#pragma unroll
            for (int i = 0; i < 2; ++i) {
                a1[i] = __builtin_amdgcn_mfma_f32_16x16x32_bf16(wa1h[i][s], g1h[s], a1[i], 0, 0, 0);
                a1[i] = __builtin_amdgcn_mfma_f32_16x16x32_bf16(wa1h[i][s], g1l[s], a1[i], 0, 0, 0);
                a1[i] = __builtin_amdgcn_mfma_f32_16x16x32_bf16(wa1l[i][s], g1h[s], a1[i], 0, 0, 0);
            }

        // ---- ew2 -> hb2[p], h2f[p] (dummy cells j>=51 land in zero-A k-pad) ----
#pragma unroll
        for (int i = 0; i < 2; ++i) {
            float cn = fmaf(sig_pre(a2[i][1]), c2[i], sig_pre(a2[i][0]) * tanh_pre(a2[i][2]));
            c2[i] = cn;
            float h = sig_pre(a2[i][3]) * tanh_pre(cn * TWOLOG2E);
            int j = jj[i], s = j >> 5, q = (j & 31) >> 3, j7 = j & 7;
            unsigned short hi = bf16_rne(h);
            ((short*)&hb2[p][0][s][q * 16 + n])[j7] = (short)hi;
            ((short*)&hb2[p][1][s][q * 16 + n])[j7] = (short)bf16_rne(h - bf16f(hi));
            h2f[p][j * 16 + n] = h;
        }

        // ---- ew1 -> hb1[p^1] ----
#pragma unroll
        for (int i = 0; i < 2; ++i) {
            float cn = fmaf(sig_pre(a1[i][1]), c1[i], sig_pre(a1[i][0]) * tanh_pre(a1[i][2]));
            c1[i] = cn;
            float h = sig_pre(a1[i][3]) * tanh_pre(cn * TWOLOG2E);
            int j = jj[i], s = j >> 5, q = (j & 31) >> 3, j7 = j & 7;
            unsigned short hi = bf16_rne(h);
            ((short*)&hb1[p ^ 1][0][s][q * 16 + n])[j7] = (short)hi;
            ((short*)&hb1[p ^ 1][1][s][q * 16 + n])[j7] = (short)bf16_rne(h - bf16f(hi));
        }

        __syncthreads();   // publishes h2(t), h2f(t), h1(t+1)
    }

    // ---- epilogue: y(2047) + final chunk flush ----
    if (wv == 7) {
        const int b = lane & 15, kg = lane >> 4;
        float a = 0.f;
#pragma unroll
        for (int it = 0; it < 13; ++it) {
            int j = kg + it * 4;
            if (j < H) a = fmaf(wlin[j], h2f[1][j * 16 + b], a);
        }
        a += __shfl_xor(a, 16, 64);
        a += __shfl_xor(a, 32, 64);
        if (kg == 0) ybf[b][63] = a + wlin[H];
#pragma unroll
        for (int r = 0; r < BB; ++r)
            out[(size_t)(b0 + r) * TSEQ + (TSEQ - 64) + lane] = ybf[r][lane];
    }
}

extern "C" void kernel_launch(void* const* d_in, const int* in_sizes, int n_in,
                              void* d_out, int out_size, void* d_ws, size_t ws_size,
                              hipStream_t stream) {
    const float* input = (const float*)d_in[0];
    const float* W_ih1 = (const float*)d_in[1];
    const float* W_hh1 = (const float*)d_in[2];
    const float* b_ih1 = (const float*)d_in[3];
    const float* b_hh1 = (const float*)d_in[4];
    const float* W_ih2 = (const float*)d_in[5];
    const float* W_hh2 = (const float*)d_in[6];
    const float* b_ih2 = (const float*)d_in[7];
    const float* b_hh2 = (const float*)d_in[8];
    const float* W_lin = (const float*)d_in[9];
    const float* b_lin = (const float*)d_in[10];

    lstm_rot_kernel<<<dim3(2048 / BB), dim3(THREADS), 0, stream>>>(
        input, W_ih1, W_hh1, b_ih1, b_hh1,
        W_ih2, W_hh2, b_ih2, b_hh2, W_lin, b_lin,
        (float*)d_out);
}

// Round 7
// 2272.432 us; speedup vs baseline: 1.1524x; 1.1524x over previous
//
#include <hip/hip_runtime.h>

#define H 51
#define TSEQ 2048
#define BB 16            // batch per block — fills all 16 MFMA columns
#define THREADS 512      // 8 waves, 2 tile-slots each, 2 waves/SIMD

typedef _Float16 __attribute__((ext_vector_type(8))) half8;  // 8 f16 (MFMA A/B frag)
typedef float    __attribute__((ext_vector_type(4))) float4v;

#define LOG2E    1.44269504f
#define TWOLOG2E 2.88539008f
#define INV4096  0.000244140625f

__device__ __forceinline__ float sig_pre(float u) {   // sigmoid(g), u = g*log2e
    return __builtin_amdgcn_rcpf(1.0f + __builtin_amdgcn_exp2f(-u));
}
__device__ __forceinline__ float tanh_pre(float u) {  // tanh(g),  u = g*2log2e
    return 1.0f - 2.0f * __builtin_amdgcn_rcpf(1.0f + __builtin_amdgcn_exp2f(u));
}

// Rotated schedule (R6): body(t) = {frag loads; [y(t-1) wave7]; mm2(t) || mm1(t+1);
// ew2(t); ew1(t+1); barrier}. h stored as SINGLE fp16 plane (halves LDS traffic).
// Weights split W = Whi + (Wlo*4096)/4096 in f16 (Wlo pre-scaled to stay normal),
// accumulated in a separate acc and folded with one fma -> weights ~exact.
// A rows repacked [i_j,f_j,g_j,o_j] per cell -> C/D reg r == gate r.
// Dummy tiles 13-15 / pad cell j>=51: zero weights, write into k-pad LDS slots
// whose A-columns are zero -> garbage never propagates; gates=0 -> h=0 (finite).
__global__ __launch_bounds__(THREADS, 2)
void lstm_f16_kernel(const float* __restrict__ input,
                     const float* __restrict__ W_ih1, const float* __restrict__ W_hh1,
                     const float* __restrict__ b_ih1, const float* __restrict__ b_hh1,
                     const float* __restrict__ W_ih2, const float* __restrict__ W_hh2,
                     const float* __restrict__ b_ih2, const float* __restrict__ b_hh2,
                     const float* __restrict__ W_lin, const float* __restrict__ b_lin,
                     float* __restrict__ out)
{
    // [parity][kstep][fraglane], single f16 plane; k-pad (k>=51) inert
    __shared__ half8 hb1[2][2][64];
    __shared__ half8 hb2[2][2][64];
    __shared__ float h2f[2][64 * 16];    // fp32 h2 (padded j<64) for y
    __shared__ float xss[2][64 * 17];    // x chunks, stride 17 conflict-free
    __shared__ float ybf[BB][64];        // y buffer (wave7-private)
    __shared__ float wlin[H + 1];

    const int tid  = threadIdx.x;
    const int wv   = tid >> 6;           // 0..7
    const int lane = tid & 63;
    const int n    = lane & 15;          // MFMA col = batch
    const int qd   = lane >> 4;          // quad
    const int b0   = blockIdx.x * BB;

    if (tid < 256) {                     // zero both parities (256 half8 per array)
        half8 z = {0,0,0,0,0,0,0,0};
        (&hb1[0][0][0])[tid] = z;
        (&hb2[0][0][0])[tid] = z;
    }
    if (tid < H)  wlin[tid] = W_lin[tid];
    if (tid == H) wlin[H]   = b_lin[0];

    // x chunk 0
#pragma unroll
    for (int r = 0; r < 2; ++r) {
        int b = wv + 8 * r;
        xss[0][lane * 17 + b] = input[(size_t)(b0 + b) * TSEQ + lane];
    }

    // ---- persistent A-fragments, split f16 (lo pre-scaled x4096), pre-scaled gates ----
    half8 wa1h[2][2], wa1l[2][2];        // W_hh1 (K=64)
    half8 wa2h[2][4], wa2l[2][4];        // s<2: W_ih2 (k=h1); s>=2: W_hh2 (k=h2)
#pragma unroll
    for (int i = 0; i < 2; ++i) {
        const int tile = wv + 8 * i;     // tiles 13..15 dummy (zero weights)
        const int arow = tile * 16 + n;
        const int cell = arow >> 2, gate = arow & 3;
        const int orow = gate * H + cell;
        const float gsc = (gate == 2) ? TWOLOG2E : LOG2E;
        const bool rok = (arow < 4 * H);
#pragma unroll
        for (int s = 0; s < 2; ++s) {
#pragma unroll
            for (int j = 0; j < 8; ++j) {
                int kk = s * 32 + qd * 8 + j;
                float w = (rok && kk < H) ? gsc * W_hh1[orow * H + kk] : 0.f;
                _Float16 hi = (_Float16)w;
                wa1h[i][s][j] = hi;
                wa1l[i][s][j] = (_Float16)((w - (float)hi) * 4096.f);
            }
        }
#pragma unroll
        for (int s = 0; s < 4; ++s) {
#pragma unroll
            for (int j = 0; j < 8; ++j) {
                int kk = s * 32 + qd * 8 + j;
                float w = 0.f;
                if (rok) {
                    if (kk < H)                       w = gsc * W_ih2[orow * H + kk];
                    else if (kk >= 64 && kk < 64 + H) w = gsc * W_hh2[orow * H + (kk - 64)];
                }
                _Float16 hi = (_Float16)w;
                wa2h[i][s][j] = hi;
                wa2l[i][s][j] = (_Float16)((w - (float)hi) * 4096.f);
            }
        }
    }

    // ---- per-lane elementwise constants (cell j = tile*4 + quad, j<64) ----
    float4v bias1v[2], wih1v[2], bias2v[2];
    int jj[2];
#pragma unroll
    for (int i = 0; i < 2; ++i) {
        const int tile = wv + 8 * i;
        const int j = tile * 4 + qd;
        jj[i] = j;
        const bool cok = (j < H);
#pragma unroll
        for (int r = 0; r < 4; ++r) {
            const float gsc = (r == 2) ? TWOLOG2E : LOG2E;
            const int orow = r * H + j;
            bias1v[i][r] = cok ? gsc * (b_ih1[orow] + b_hh1[orow]) : 0.f;
            wih1v[i][r]  = cok ? gsc * W_ih1[orow] : 0.f;
            bias2v[i][r] = cok ? gsc * (b_ih2[orow] + b_hh2[orow]) : 0.f;
        }
    }

    float c1[2] = {0.f, 0.f};
    float c2[2] = {0.f, 0.f};

    __syncthreads();   // zeros + wlin + x chunk 0 visible

    // ---- prologue: h1(0) = ew(bias1 + Wih1*x(0))   (h1(-1)=0 -> no MFMA) ----
    {
        const float xb = xss[0][n];
#pragma unroll
        for (int i = 0; i < 2; ++i) {
            float4v a;
#pragma unroll
            for (int r = 0; r < 4; ++r) a[r] = fmaf(wih1v[i][r], xb, bias1v[i][r]);
            float cn = fmaf(sig_pre(a[1]), c1[i], sig_pre(a[0]) * tanh_pre(a[2]));
            c1[i] = cn;
            float h = sig_pre(a[3]) * tanh_pre(cn * TWOLOG2E);
            int j = jj[i], s = j >> 5, q = (j & 31) >> 3, j7 = j & 7;
            ((_Float16*)&hb1[0][s][q * 16 + n])[j7] = (_Float16)h;
        }
    }
    __syncthreads();   // h1(0) published

#pragma unroll 1
    for (int t = 0; t < TSEQ; ++t) {
        const int p = t & 1;

        // mid-chunk x prefetch (barrier-free double buffer)
        if ((t & 63) == 32 && t + 32 < TSEQ) {
            const int cp = (t >> 6) & 1;
#pragma unroll
            for (int r = 0; r < 2; ++r) {
                int b = wv + 8 * r;
                xss[cp ^ 1][lane * 17 + b] = input[(size_t)(b0 + b) * TSEQ + (t + 32) + lane];
            }
        }

        // ---- frag loads: h1(t) [parity p], h2(t-1) [parity p^1] — 4 b128 ----
        half8 g1[2], g2[2];
#pragma unroll
        for (int s = 0; s < 2; ++s) {
            g1[s] = hb1[p][s][lane];
            g2[s] = hb2[p ^ 1][s][lane];
        }

        // ---- y(t-1) + chunk flush: wave7 only ----
        if (wv == 7 && t > 0) {
            const int b = lane & 15, kg = lane >> 4;
            float a = 0.f;
#pragma unroll
            for (int it = 0; it < 13; ++it) {
                int j = kg + it * 4;
                if (j < H) a = fmaf(wlin[j], h2f[p ^ 1][j * 16 + b], a);
            }
            a += __shfl_xor(a, 16, 64);
            a += __shfl_xor(a, 32, 64);
            if (kg == 0) ybf[b][(t - 1) & 63] = a + wlin[H];
            if ((t & 63) == 0) {          // flush y[t-64 .. t-1]
                int tb = t - 64;
#pragma unroll
                for (int r = 0; r < BB; ++r)
                    out[(size_t)(b0 + r) * TSEQ + tb + lane] = ybf[r][lane];
            }
        }

        // ======== chain A: mm2(t)  (g1=h1(t), g2=h2(t-1)) ========
        float4v a2[2], a2l[2];
#pragma unroll
        for (int i = 0; i < 2; ++i) {
            a2[i]  = bias2v[i];
            a2l[i] = (float4v){0.f, 0.f, 0.f, 0.f};
        }
#pragma unroll
        for (int s = 0; s < 2; ++s)
#pragma unroll
            for (int i = 0; i < 2; ++i) {
                a2[i]  = __builtin_amdgcn_mfma_f32_16x16x32_f16(wa2h[i][s],     g1[s], a2[i],  0, 0, 0);
                a2l[i] = __builtin_amdgcn_mfma_f32_16x16x32_f16(wa2l[i][s],     g1[s], a2l[i], 0, 0, 0);
                a2[i]  = __builtin_amdgcn_mfma_f32_16x16x32_f16(wa2h[i][s + 2], g2[s], a2[i],  0, 0, 0);
                a2l[i] = __builtin_amdgcn_mfma_f32_16x16x32_f16(wa2l[i][s + 2], g2[s], a2l[i], 0, 0, 0);
            }

        // ======== chain B: mm1(t+1)  (g1=h1(t), x(t+1)) ========
        // t=2047: writes garbage h1(2048) into hb1[0] — never read. Branch-free.
        const int t1 = t + 1;
        const float xb = xss[(t1 >> 6) & 1][(t1 & 63) * 17 + n];
        float4v a1[2], a1l[2];
#pragma unroll
        for (int i = 0; i < 2; ++i) {
#pragma unroll
            for (int r = 0; r < 4; ++r)
                a1[i][r] = fmaf(wih1v[i][r], xb, bias1v[i][r]);
            a1l[i] = (float4v){0.f, 0.f, 0.f, 0.f};
        }
#pragma unroll
        for (int s = 0; s < 2; ++s)
#pragma unroll
            for (int i = 0; i < 2; ++i) {
                a1[i]  = __builtin_amdgcn_mfma_f32_16x16x32_f16(wa1h[i][s], g1[s], a1[i],  0, 0, 0);
                a1l[i] = __builtin_amdgcn_mfma_f32_16x16x32_f16(wa1l[i][s], g1[s], a1l[i], 0, 0, 0);
            }

        // ---- ew2 -> hb2[p], h2f[p] ----
#pragma unroll
        for (int i = 0; i < 2; ++i) {
#pragma unroll
            for (int r = 0; r < 4; ++r)
                a2[i][r] = fmaf(a2l[i][r], INV4096, a2[i][r]);
            float cn = fmaf(sig_pre(a2[i][1]), c2[i], sig_pre(a2[i][0]) * tanh_pre(a2[i][2]));
            c2[i] = cn;
            float h = sig_pre(a2[i][3]) * tanh_pre(cn * TWOLOG2E);
            int j = jj[i], s = j >> 5, q = (j & 31) >> 3, j7 = j & 7;
            ((_Float16*)&hb2[p][s][q * 16 + n])[j7] = (_Float16)h;
            h2f[p][j * 16 + n] = h;
        }

        // ---- ew1 -> hb1[p^1] ----
#pragma unroll
        for (int i = 0; i < 2; ++i) {
#pragma unroll
            for (int r = 0; r < 4; ++r)
                a1[i][r] = fmaf(a1l[i][r], INV4096, a1[i][r]);
            float cn = fmaf(sig_pre(a1[i][1]), c1[i], sig_pre(a1[i][0]) * tanh_pre(a1[i][2]));
            c1[i] = cn;
            float h = sig_pre(a1[i][3]) * tanh_pre(cn * TWOLOG2E);
            int j = jj[i], s = j >> 5, q = (j & 31) >> 3, j7 = j & 7;
            ((_Float16*)&hb1[p ^ 1][s][q * 16 + n])[j7] = (_Float16)h;
        }

        __syncthreads();   // publishes h2(t), h2f(t), h1(t+1)
    }

    // ---- epilogue: y(2047) + final chunk flush ----
    if (wv == 7) {
        const int b = lane & 15, kg = lane >> 4;
        float a = 0.f;
#pragma unroll
        for (int it = 0; it < 13; ++it) {
            int j = kg + it * 4;
            if (j < H) a = fmaf(wlin[j], h2f[1][j * 16 + b], a);
        }
        a += __shfl_xor(a, 16, 64);
        a += __shfl_xor(a, 32, 64);
        if (kg == 0) ybf[b][63] = a + wlin[H];
#pragma unroll
        for (int r = 0; r < BB; ++r)
            out[(size_t)(b0 + r) * TSEQ + (TSEQ - 64) + lane] = ybf[r][lane];
    }
}

extern "C" void kernel_launch(void* const* d_in, const int* in_sizes, int n_in,
                              void* d_out, int out_size, void* d_ws, size_t ws_size,
                              hipStream_t stream) {
    const float* input = (const float*)d_in[0];
    const float* W_ih1 = (const float*)d_in[1];
    const float* W_hh1 = (const float*)d_in[2];
    const float* b_ih1 = (const float*)d_in[3];
    const float* b_hh1 = (const float*)d_in[4];
    const float* W_ih2 = (const float*)d_in[5];
    const float* W_hh2 = (const float*)d_in[6];
    const float* b_ih2 = (const float*)d_in[7];
    const float* b_hh2 = (const float*)d_in[8];
    const float* W_lin = (const float*)d_in[9];
    const float* b_lin = (const float*)d_in[10];

    lstm_f16_kernel<<<dim3(2048 / BB), dim3(THREADS), 0, stream>>>(
        input, W_ih1, W_hh1, b_ih1, b_hh1,
        W_ih2, W_hh2, b_ih2, b_hh2, W_lin, b_lin,
        (float*)d_out);
}